// Round 5
// baseline (222.866 us; speedup 1.0000x reference)
//
#include <hip/hip_runtime.h>
#include <hip/hip_fp16.h>
#include <hip/hip_cooperative_groups.h>
#include <math.h>

namespace cg = cooperative_groups;

#define NH 4        // heads
#define DD 64       // out features per head
#define NF 256      // NH*DD
#define KF 128      // in features
#define NN 4096     // nodes
#define NB 2        // batch
#define NG 8        // NB*NH groups
#define CH 32       // scan chunk length
#define NCH 128     // NN / CH
#define SUB 8       // elements per wave within a chunk (4 waves * 8 = CH)

// ---------------- Kernel 1: H = X @ W  (fp32 math, fp16 H store), fused s/d epilogue ----------------
__global__ __launch_bounds__(256) void k_gemm(const float* __restrict__ X,
                                              const float* __restrict__ W,
                                              const float* __restrict__ a_src,
                                              const float* __restrict__ a_dst,
                                              __half* __restrict__ Hout,
                                              float* __restrict__ s_arr,
                                              float* __restrict__ d_arr) {
  __shared__ float As[64][132];
  const int bm = blockIdx.x;               // 0..127
  const int bn = blockIdx.y;               // 0..3 (head)
  const int tid = threadIdx.x;

  for (int i = tid; i < 64 * 32; i += 256) {
    int r = i >> 5, c4 = i & 31;
    float4 v = *(const float4*)(X + ((size_t)(bm * 64 + r)) * KF + c4 * 4);
    *(float4*)&As[r][c4 * 4] = v;
  }
  __syncthreads();

  const int ty = tid >> 4, tx = tid & 15;
  const int col0 = bn * 64 + tx * 4;
  const float* Wp = W + col0;              // stride NF
  float acc[4][4] = {{0.f}};

  #pragma unroll 2
  for (int k4 = 0; k4 < 32; ++k4) {
    float4 a[4];
    #pragma unroll
    for (int i = 0; i < 4; ++i) a[i] = *(const float4*)&As[ty * 4 + i][k4 * 4];
    #pragma unroll
    for (int jk = 0; jk < 4; ++jk) {
      float4 b = *(const float4*)(Wp + (size_t)(k4 * 4 + jk) * NF);
      #pragma unroll
      for (int i = 0; i < 4; ++i) {
        float av = ((const float*)&a[i])[jk];
        acc[i][0] += av * b.x;
        acc[i][1] += av * b.y;
        acc[i][2] += av * b.z;
        acc[i][3] += av * b.w;
      }
    }
  }

  const float4 asv = *(const float4*)(a_src + bn * 64 + tx * 4);
  const float4 adv = *(const float4*)(a_dst + bn * 64 + tx * 4);
  const int grow0 = bm * 64 + ty * 4;
  #pragma unroll
  for (int i = 0; i < 4; ++i) {
    int grow = grow0 + i;
    union { __half2 h2[2]; float2 f2; } u;
    u.h2[0] = __floats2half2_rn(acc[i][0], acc[i][1]);
    u.h2[1] = __floats2half2_rn(acc[i][2], acc[i][3]);
    *(float2*)&Hout[(size_t)grow * NF + col0] = u.f2;
    float ps = acc[i][0] * asv.x + acc[i][1] * asv.y + acc[i][2] * asv.z + acc[i][3] * asv.w;
    float pd = acc[i][0] * adv.x + acc[i][1] * adv.y + acc[i][2] * adv.z + acc[i][3] * adv.w;
    #pragma unroll
    for (int off = 1; off < 16; off <<= 1) {
      ps += __shfl_xor(ps, off);
      pd += __shfl_xor(pd, off);
    }
    if (tx == 0) {
      int b = grow >> 12, n = grow & (NN - 1);
      int g = b * NH + bn;
      s_arr[g * NN + n] = ps;
      d_arr[g * NN + n] = pd;
    }
  }
}

// ---------------- Kernel 2: per-(b,h) bitonic sort, 4-consecutive ownership ----------------
__global__ __launch_bounds__(1024) void k_sort(const float* __restrict__ d_arr,
                                               float* __restrict__ dsort,
                                               int* __restrict__ perm) {
  __shared__ float4 skey[1024];
  __shared__ int4 sidx[1024];
  const int g = blockIdx.x;
  const int tid = threadIdx.x;

  float kk[4];
  int ii[4];
  {
    float4 kv = *(const float4*)(d_arr + g * NN + 4 * tid);
    kk[0] = kv.x; kk[1] = kv.y; kk[2] = kv.z; kk[3] = kv.w;
    ii[0] = 4 * tid; ii[1] = 4 * tid + 1; ii[2] = 4 * tid + 2; ii[3] = 4 * tid + 3;
  }

  #define CE(a, b, asc)                                            \
    do { if ((kk[a] > kk[b]) == (asc)) {                           \
      float tk = kk[a]; kk[a] = kk[b]; kk[b] = tk;                 \
      int ti = ii[a]; ii[a] = ii[b]; ii[b] = ti; } } while (0)

  CE(0, 1, true);
  CE(2, 3, false);

  #pragma unroll
  for (int k = 4; k <= NN; k <<= 1) {
    const bool asc = (tid & (k >> 2)) == 0;
    #pragma unroll
    for (int j = k >> 1; j > 0; j >>= 1) {
      if (j >= 256) {
        const int tdist = j >> 2;
        skey[tid] = make_float4(kk[0], kk[1], kk[2], kk[3]);
        sidx[tid] = make_int4(ii[0], ii[1], ii[2], ii[3]);
        __syncthreads();
        float4 pk4 = skey[tid ^ tdist];
        int4 pi4 = sidx[tid ^ tdist];
        const bool lower = (tid & tdist) == 0;
        #pragma unroll
        for (int r = 0; r < 4; ++r) {
          float pk = (&pk4.x)[r];
          int pid = (&pi4.x)[r];
          float kl = lower ? kk[r] : pk;
          float kh = lower ? pk : kk[r];
          if ((kl > kh) == asc) { kk[r] = pk; ii[r] = pid; }
        }
        __syncthreads();
      } else if (j >= 4) {
        const int dist = j >> 2;
        const bool lower = (tid & dist) == 0;
        #pragma unroll
        for (int r = 0; r < 4; ++r) {
          float pk = __shfl_xor(kk[r], dist);
          int pid = __shfl_xor(ii[r], dist);
          float kl = lower ? kk[r] : pk;
          float kh = lower ? pk : kk[r];
          if ((kl > kh) == asc) { kk[r] = pk; ii[r] = pid; }
        }
      } else if (j == 2) {
        CE(0, 2, asc);
        CE(1, 3, asc);
      } else {
        CE(0, 1, asc);
        CE(2, 3, asc);
      }
    }
  }
  #undef CE

  *(float4*)(dsort + g * NN + 4 * tid) = make_float4(kk[0], kk[1], kk[2], kk[3]);
  *(int4*)(perm + g * NN + 4 * tid) = make_int4(ii[0], ii[1], ii[2], ii[3]);
}

// ---------------- Kernel 3 (cooperative): scan phases A/B + output phase C ----------------
__global__ __launch_bounds__(256, 4) void k_scan_out(const __half* __restrict__ Hmat,
                                                     const float* __restrict__ dsort,
                                                     const int* __restrict__ perm,
                                                     const float* __restrict__ s_arr,
                                                     float* __restrict__ chunkP, float* __restrict__ chunkS,
                                                     float* __restrict__ chunkPw, float* __restrict__ chunkSw,
                                                     __half* __restrict__ Ph, __half* __restrict__ Sh,
                                                     float* __restrict__ Pexp, float* __restrict__ Sexp,
                                                     const float* __restrict__ bias,
                                                     float* __restrict__ out) {
  cg::grid_group grid = cg::this_grid();
  __shared__ float subP[4][64], subS[4][64];
  __shared__ float subPw[4], subSw[4];
  __shared__ float ppart[4][64], spart[4][64];

  const int blk = blockIdx.x;   // 0..1023
  const int ch = blk & 127;
  const int g = blk >> 7;
  const int b = g >> 2, h = g & 3;
  const int c = threadIdx.x & 63;
  const int w = threadIdx.x >> 6;
  const int gNN = g * NN;
  const size_t bNN = (size_t)b * NN;
  const int h64 = h * 64;
  const float dmax = dsort[gNN + NN - 1];
  const int kw0 = ch * CH + w * SUB;

  // ===== Phase A: batched loads + sub-chunk sums (registers persist into phase B) =====
  int j8[SUB]; float d8[SUB], hv8[SUB], wp8[SUB], ws8[SUB];
  #pragma unroll
  for (int l = 0; l < SUB; ++l) j8[l] = perm[gNN + kw0 + l];
  #pragma unroll
  for (int l = 0; l < SUB; ++l) d8[l] = dsort[gNN + kw0 + l];
  #pragma unroll
  for (int l = 0; l < SUB; ++l) hv8[l] = __half2float(Hmat[(bNN + j8[l]) * NF + h64 + c]);

  float pa = 0.f, sa = 0.f, pwl = 0.f, swl = 0.f;
  #pragma unroll
  for (int l = 0; l < SUB; ++l) {
    wp8[l] = __expf(0.2f * (d8[l] - dmax));
    ws8[l] = __expf(d8[l] - dmax);
    pa += wp8[l] * hv8[l]; sa += ws8[l] * hv8[l];
    pwl += wp8[l]; swl += ws8[l];
  }
  subP[w][c] = pa; subS[w][c] = sa;
  if (c == 0) { subPw[w] = pwl; subSw[w] = swl; }
  __syncthreads();

  if (w == 0) {
    float tp = subP[0][c] + subP[1][c] + subP[2][c] + subP[3][c];
    float ts = subS[0][c] + subS[1][c] + subS[2][c] + subS[3][c];
    chunkP[(g * NCH + ch) * 64 + c] = tp;
    chunkS[(g * NCH + ch) * 64 + c] = ts;
    if (c == 0) {
      chunkPw[g * NCH + ch] = subPw[0] + subPw[1] + subPw[2] + subPw[3];
      chunkSw[g * NCH + ch] = subSw[0] + subSw[1] + subSw[2] + subSw[3];
    }
  }

  grid.sync();

  // ===== Phase B: cross-chunk offsets + register replay, write Ph/Sh/Pexp/Sexp =====
  float pp = 0.f, sp = 0.f;
  for (int t = w; t < ch; t += 4)            pp += chunkP[(g * NCH + t) * 64 + c];
  for (int t = ch + 1 + w; t < NCH; t += 4)  sp += chunkS[(g * NCH + t) * 64 + c];
  ppart[w][c] = pp; spart[w][c] = sp;

  float w1 = chunkPw[g * NCH + c];
  float w2 = chunkPw[g * NCH + 64 + c];
  float pwo = (c < ch ? w1 : 0.f) + (c + 64 < ch ? w2 : 0.f);
  float u1 = chunkSw[g * NCH + c];
  float u2 = chunkSw[g * NCH + 64 + c];
  float swo = (c > ch ? u1 : 0.f) + (c + 64 > ch ? u2 : 0.f);
  #pragma unroll
  for (int off = 1; off < 64; off <<= 1) {
    pwo += __shfl_xor(pwo, off);
    swo += __shfl_xor(swo, off);
  }

  __syncthreads();

  float poffv = ppart[0][c] + ppart[1][c] + ppart[2][c] + ppart[3][c];
  float soffv = spart[0][c] + spart[1][c] + spart[2][c] + spart[3][c];
  float intraP = 0.f, intraS = 0.f, intraPw = 0.f, intraSw = 0.f;
  #pragma unroll
  for (int t = 0; t < 4; ++t) {
    if (t < w) { intraP += subP[t][c]; intraPw += subPw[t]; }
    if (t > w) { intraS += subS[t][c]; intraSw += subSw[t]; }
  }

  float rp = poffv + intraP, rw = pwo + intraPw;
  #pragma unroll
  for (int l = 0; l < SUB; ++l) {
    int k = kw0 + l;
    rp += wp8[l] * hv8[l]; rw += wp8[l];
    Ph[((size_t)(gNN + k)) * 64 + c] = __float2half(rp);
    if (c == 0) Pexp[gNN + k] = rw;
  }
  float rs = soffv + intraS, rsw = swo + intraSw;
  #pragma unroll
  for (int l = SUB - 1; l >= 0; --l) {
    int k = kw0 + l;
    rs += ws8[l] * hv8[l]; rsw += ws8[l];
    Sh[((size_t)(gNN + k)) * 64 + c] = __float2half(rs);
    if (c == 0) Sexp[gNN + k] = rsw;
  }

  grid.sync();

  // ===== Phase C: per-row combine + bias + ELU (8 rows per wave, batched ILP) =====
  const int lane = c;
  const int task0 = blk * 32 + w * 8;          // 8 consecutive row-tasks, same group
  const int gc = task0 >> 12;
  const int i0 = task0 & (NN - 1);
  const int bc = gc >> 2, hc = gc & 3;
  const float* ds = dsort + (size_t)gc * NN;
  const float dmaxc = ds[NN - 1];
  const float biasv = bias[hc * 64 + lane];

  float si8[8];
  #pragma unroll
  for (int l = 0; l < 8; ++l) si8[l] = s_arr[gc * NN + i0 + l];

  const float probe1 = ds[lane * 64 + 63];     // shared across the 8 rows
  int b1[8];
  #pragma unroll
  for (int l = 0; l < 8; ++l) {
    unsigned long long m1 = __ballot(probe1 <= -si8[l]);
    b1[l] = __popcll(m1);
  }
  float probe2[8];
  #pragma unroll
  for (int l = 0; l < 8; ++l)
    probe2[l] = (b1[l] < 64) ? ds[b1[l] * 64 + lane] : 0.f;
  int m8[8];
  #pragma unroll
  for (int l = 0; l < 8; ++l) {
    if (b1[l] == 64) m8[l] = NN;
    else {
      unsigned long long m2 = __ballot(probe2[l] <= -si8[l]);
      m8[l] = b1[l] * 64 + __popcll(m2);
    }
  }

  float numA[8], denA[8], numB[8], denB[8];
  #pragma unroll
  for (int l = 0; l < 8; ++l) {
    int m = m8[l];
    if (m < NN) {
      numA[l] = __half2float(Sh[((size_t)(gc * NN + m)) * 64 + lane]);
      denA[l] = Sexp[gc * NN + m];
    } else { numA[l] = 0.f; denA[l] = 0.f; }
    if (m > 0) {
      numB[l] = __half2float(Ph[((size_t)(gc * NN + m - 1)) * 64 + lane]);
      denB[l] = Pexp[gc * NN + m - 1];
    } else { numB[l] = 0.f; denB[l] = 0.f; }
  }

  #pragma unroll
  for (int l = 0; l < 8; ++l) {
    const float sdm = si8[l] + dmaxc;
    const float mx = sdm > 0.f ? sdm : 0.2f * sdm;
    const float alpha = __expf(sdm - mx);
    const float beta = __expf(0.2f * sdm - mx);
    const float den = alpha * denA[l] + beta * denB[l];
    float val = (alpha * numA[l] + beta * numB[l]) / den + biasv;
    float o = val > 0.f ? val : expm1f(val);
    out[((size_t)(bc * NN + i0 + l)) * NF + hc * 64 + lane] = o;
  }
}

extern "C" void kernel_launch(void* const* d_in, const int* in_sizes, int n_in,
                              void* d_out, int out_size, void* d_ws, size_t ws_size,
                              hipStream_t stream) {
  const float* X = (const float*)d_in[0];       // [2,4096,128]
  const float* W = (const float*)d_in[1];       // [128,256]
  const float* a_src = (const float*)d_in[2];   // [4,64,1]
  const float* a_dst = (const float*)d_in[3];   // [4,64,1]
  const float* bias = (const float*)d_in[4];    // [256]
  float* out = (float*)d_out;                   // [2,4096,256]

  float* ws = (float*)d_ws;
  float* s_arr = ws;                    // 8*4096
  float* d_arr = s_arr + NG * NN;       // 8*4096
  float* dsort = d_arr + NG * NN;       // 8*4096
  int* perm = (int*)(dsort + NG * NN);  // 8*4096
  float* Pexp = (float*)(perm + NG * NN);
  float* Sexp = Pexp + NG * NN;
  float* chunkP = Sexp + NG * NN;       // 8*128*64
  float* chunkS = chunkP + NG * NCH * 64;
  float* chunkPw = chunkS + NG * NCH * 64;  // 8*128
  float* chunkSw = chunkPw + NG * NCH;
  __half* Hmat = (__half*)(chunkSw + NG * NCH);     // 2*4096*256 halves (4 MB)
  __half* Ph = Hmat + (size_t)NB * NN * NF;         // 8*4096*64 halves
  __half* Sh = Ph + (size_t)NG * NN * 64;

  k_gemm<<<dim3(128, 4), 256, 0, stream>>>(X, W, a_src, a_dst, Hmat, s_arr, d_arr);
  k_sort<<<NG, 1024, 0, stream>>>(d_arr, dsort, perm);

  void* args[] = {(void*)&Hmat, (void*)&dsort, (void*)&perm, (void*)&s_arr,
                  (void*)&chunkP, (void*)&chunkS, (void*)&chunkPw, (void*)&chunkSw,
                  (void*)&Ph, (void*)&Sh, (void*)&Pexp, (void*)&Sexp,
                  (void*)&bias, (void*)&out};
  hipLaunchCooperativeKernel((const void*)k_scan_out, dim3(1024), dim3(256), args, 0, stream);
}